// Round 5
// baseline (239.670 us; speedup 1.0000x reference)
//
#include <hip/hip_runtime.h>
#include <hip/hip_bf16.h>
#include <cstddef>

typedef __attribute__((ext_vector_type(8))) short short8;   // 8 x bf16
typedef __attribute__((ext_vector_type(4))) float f32x4;    // MFMA accumulator

#define MFMA16(a, b, c) __builtin_amdgcn_mfma_f32_16x16x32_bf16((a), (b), (c), 0, 0, 0)
#define NBLK 256

static __device__ __forceinline__ unsigned short f2bf(float f) {   // RNE
    unsigned int u = __float_as_uint(f);
    u = (u + 0x7FFFu + ((u >> 16) & 1u)) >> 16;
    return (unsigned short)u;
}
static __device__ __forceinline__ float bf2f(unsigned short h) {
    return __uint_as_float(((unsigned int)h) << 16);
}
static __device__ __forceinline__ float silu_f(float v) { return v / (1.f + expf(-v)); }

// ws layout (bf16 element offsets, all multiples of 8 -> 16B aligned)
enum : size_t {
    O_X    = 0,                        // 512 x 512
    O_WIP  = O_X    + 512 * 512,       // 2048 x 512
    O_WXP  = O_WIP  + 2048 * 512,      // 288 x 1024
    O_WDT  = O_WXP  + 288 * 1024,      // 1024 x 32
    O_WOUT = O_WDT  + 1024 * 32,       // 512 x 1024
    O_WFC1 = O_WOUT + 512 * 1024,      // 256 x 512
    O_XIN  = O_WFC1 + 256 * 512,       // 512 x 1024
    O_SZ   = O_XIN  + 512 * 1024,      // 512 x 1024
    O_XDBL = O_SZ   + 512 * 1024,      // 512 x 288
    O_Y    = O_XDBL + 512 * 288,       // 512 x 1024
    O_MOUT = O_Y    + 512 * 1024,      // 512 x 512
    O_END  = O_MOUT + 512 * 512,       // barrier counter lives here (4B-aligned)
};

static __device__ __forceinline__ void cvt_seg(const float* __restrict__ s,
                                               unsigned short* __restrict__ d,
                                               int n, int gt, int np)
{
    for (int i = gt * 4; i < n; i += np * 4) {
        float4 v = *reinterpret_cast<const float4*>(s + i);
        ushort4 o;
        o.x = f2bf(v.x); o.y = f2bf(v.y); o.z = f2bf(v.z); o.w = f2bf(v.w);
        *reinterpret_cast<ushort4*>(d + i) = o;
    }
}

// Device-scope grid barrier: monotonic counter, release-add + acquire-spin.
// Agent-scope release emits the L2 writeback, acquire the invalidate, so
// cross-XCD activation traffic is coherent after each phase.
static __device__ __forceinline__ void grid_barrier(unsigned* cnt, unsigned target)
{
    __syncthreads();
    if (threadIdx.x == 0) {
        __hip_atomic_fetch_add(cnt, 1u, __ATOMIC_RELEASE, __HIP_MEMORY_SCOPE_AGENT);
        while (__hip_atomic_load(cnt, __ATOMIC_ACQUIRE, __HIP_MEMORY_SCOPE_AGENT) < target)
            __builtin_amdgcn_s_sleep(2);
    }
    __syncthreads();
}

// ---------------------------------------------------------------------------
// Persistent kernel: all 6 stages, 256 blocks x 256 threads (1 block/CU).
// ---------------------------------------------------------------------------
__global__ __launch_bounds__(256, 2) void k_net(
    const float* __restrict__ x,    const float* __restrict__ wip,
    const float* __restrict__ wxp,  const float* __restrict__ wdt,
    const float* __restrict__ wout, const float* __restrict__ wfc1,
    const float* __restrict__ cw,   const float* __restrict__ cb,
    const float* __restrict__ dtb,  const float* __restrict__ Dv,
    const float* __restrict__ bfc1, const float* __restrict__ wfc5,
    const float* __restrict__ bfc5,
    unsigned short* __restrict__ wsb, unsigned* __restrict__ bar,
    float* __restrict__ out)
{
    __shared__ float smem[16 * 72];           // phase 3: bcp[16*17]+bc[16]; phase 5: red[16*72]
    const int tid  = threadIdx.x;
    const int bid  = blockIdx.x;
    const int w    = tid >> 6;                // wave 0..3
    const int lane = tid & 63;
    const int l15  = lane & 15;
    const int g    = lane >> 4;               // k-group 0..3

    // ================= phase 0: f32 -> bf16 convert =========================
    {
        const int gt = bid * 256 + tid, np = NBLK * 256;
        cvt_seg(x,    wsb + O_X,    512 * 512,  gt, np);
        cvt_seg(wip,  wsb + O_WIP,  2048 * 512, gt, np);
        cvt_seg(wxp,  wsb + O_WXP,  288 * 1024, gt, np);
        cvt_seg(wdt,  wsb + O_WDT,  1024 * 32,  gt, np);
        cvt_seg(wout, wsb + O_WOUT, 512 * 1024, gt, np);
        cvt_seg(wfc1, wsb + O_WFC1, 256 * 512,  gt, np);
    }
    grid_barrier(bar, NBLK * 1);

    // ================= phase 1: xz = x @ wip^T + conv/silu ==================
    // 32 n-tiles(64) x 8 m-tiles(64); wave = 16 rows x 64 cols. Blocks sharing
    // an n-tile are spaced 32 apart -> same XCD -> weight-tile L2 reuse.
    {
        const int n0 = (bid & 31) * 64;
        const int m0 = (bid >> 5) * 64 + w * 16;
        const unsigned short* ab = wsb + O_X   + (size_t)(m0 + l15) * 512 + g * 8;
        const unsigned short* bb = wsb + O_WIP + (size_t)(n0 + l15) * 512 + g * 8;
        f32x4 acc[4] = {};
#pragma unroll 4
        for (int k0 = 0; k0 < 512; k0 += 32) {
            short8 a = *reinterpret_cast<const short8*>(ab + k0);
#pragma unroll
            for (int f = 0; f < 4; ++f) {
                short8 b = *reinterpret_cast<const short8*>(bb + f * 16 * 512 + k0);
                acc[f] = MFMA16(a, b, acc[f]);
            }
        }
        const bool xhalf = (n0 < 1024);
        unsigned short* dst = wsb + (xhalf ? O_XIN : O_SZ);
#pragma unroll
        for (int f = 0; f < 4; ++f) {
            int n = n0 + f * 16 + l15;
            int c = xhalf ? n : n - 1024;
            float cwv = 0.f, cbv = 0.f;
            if (xhalf) { cwv = cw[2 * n + 1]; cbv = cb[n]; }
#pragma unroll
            for (int i = 0; i < 4; ++i) {
                int r = m0 + g * 4 + i;
                float v = acc[f][i];
                v = xhalf ? silu_f(cbv + cwv * v) : silu_f(v);
                dst[(size_t)r * 1024 + c] = f2bf(v);
            }
        }
    }
    grid_barrier(bar, NBLK * 2);

    // ================= phase 2: xdbl = xin @ wxp^T (N=288, K=1024) ==========
    // wave-level units: 18 n-tiles(16) x 32 m-tiles(16) = 576 of 1024 waves.
    {
        const int u = bid * 4 + w;
        if (u < 576) {
            const int n0 = (u % 18) * 16;
            const int m0 = (u / 18) * 16;
            const unsigned short* ab = wsb + O_XIN + (size_t)(m0 + l15) * 1024 + g * 8;
            const unsigned short* bb = wsb + O_WXP + (size_t)(n0 + l15) * 1024 + g * 8;
            f32x4 acc = {};
#pragma unroll 4
            for (int k0 = 0; k0 < 1024; k0 += 32) {
                short8 a = *reinterpret_cast<const short8*>(ab + k0);
                short8 b = *reinterpret_cast<const short8*>(bb + k0);
                acc = MFMA16(a, b, acc);
            }
            unsigned short* xd = wsb + O_XDBL;
#pragma unroll
            for (int i = 0; i < 4; ++i)
                xd[(size_t)(m0 + g * 4 + i) * 288 + n0 + l15] = f2bf(acc[i]);
        }
    }
    grid_barrier(bar, NBLK * 3);

    // ================= phase 3: dt/softplus + bc + y (N=1024, K=32) =========
    // 128 blocks: 4 n-tiles(256) x 32 m-tiles(16 rows).
    if (bid < 128) {
        const int m0 = (bid >> 2) * 16;
        const int n0 = (bid & 3) * 256;
        const unsigned short* xd = wsb + O_XDBL;
        float* bcp  = smem;              // [16][17]
        float* bc_s = smem + 16 * 17;    // [16]
        {   // bc[r] = sum_{s<128} Bm[r,s]*Cm[r,s]  (cols 32..159 x 160..287)
            int r = tid >> 4, p = tid & 15;
            const unsigned short* row = xd + (size_t)(m0 + r) * 288;
            float s = 0.f;
#pragma unroll
            for (int q = 0; q < 8; ++q)
                s += bf2f(row[32 + p * 8 + q]) * bf2f(row[160 + p * 8 + q]);
            bcp[r * 17 + p] = s;
        }
        short8 a = *reinterpret_cast<const short8*>(xd + (size_t)(m0 + l15) * 288 + g * 8);
        __syncthreads();
        if (tid < 16) {
            float s = 0.f;
#pragma unroll
            for (int p = 0; p < 16; ++p) s += bcp[tid * 17 + p];
            bc_s[tid] = s;
        }
        __syncthreads();

        const unsigned short* wdtb = wsb + O_WDT;
        const unsigned short* xinb = wsb + O_XIN;
        const unsigned short* szb  = wsb + O_SZ;
        unsigned short* yb = wsb + O_Y;
        const f32x4 z4 = {0.f, 0.f, 0.f, 0.f};
#pragma unroll
        for (int f = 0; f < 4; ++f) {
            int n = n0 + w * 64 + f * 16 + l15;   // 0..1023
            short8 b = *reinterpret_cast<const short8*>(wdtb + (size_t)n * 32 + g * 8);
            f32x4 acc = MFMA16(a, b, z4);
            float dtbv = dtb[n], Dvv = Dv[n];
#pragma unroll
            for (int i = 0; i < 4; ++i) {
                int r = m0 + g * 4 + i;
                float dtv = acc[i] + dtbv;
                dtv = (dtv > 20.f) ? dtv : log1pf(expf(dtv));   // softplus
                float yv = bf2f(xinb[(size_t)r * 1024 + n]) *
                           (dtv * bc_s[g * 4 + i] + Dvv) *
                           bf2f(szb[(size_t)r * 1024 + n]);
                yb[(size_t)r * 1024 + n] = f2bf(yv);
            }
        }
    }
    grid_barrier(bar, NBLK * 4);

    // ================= phase 4: mout = y @ wout^T (N=512, K=1024) ===========
    // 32 m-tiles(16 rows) x 8 n-tiles(64); wave = 16x16 tile. Blocks sharing
    // an n-tile spaced 8 apart -> same XCD.
    {
        const int n0 = (bid & 7) * 64 + w * 16;
        const int m0 = (bid >> 3) * 16;
        const unsigned short* ab = wsb + O_Y    + (size_t)(m0 + l15) * 1024 + g * 8;
        const unsigned short* bb = wsb + O_WOUT + (size_t)(n0 + l15) * 1024 + g * 8;
        f32x4 acc = {};
#pragma unroll 4
        for (int k0 = 0; k0 < 1024; k0 += 32) {
            short8 a = *reinterpret_cast<const short8*>(ab + k0);
            short8 b = *reinterpret_cast<const short8*>(bb + k0);
            acc = MFMA16(a, b, acc);
        }
        unsigned short* mo = wsb + O_MOUT;
#pragma unroll
        for (int i = 0; i < 4; ++i)
            mo[(size_t)(m0 + g * 4 + i) * 512 + n0 + l15] = f2bf(acc[i]);
    }
    grid_barrier(bar, NBLK * 5);

    // ================= phase 5: fc1 + head (32 blocks, 16 rows each) ========
    if (bid < 32) {
        const int m0 = bid * 16;
        const unsigned short* ab = wsb + O_MOUT + (size_t)(m0 + l15) * 512 + g * 8;
        const unsigned short* bb = wsb + O_WFC1 + (size_t)(w * 64 + l15) * 512 + g * 8;
        f32x4 acc[4] = {};
#pragma unroll 4
        for (int k0 = 0; k0 < 512; k0 += 32) {
            short8 a = *reinterpret_cast<const short8*>(ab + k0);
#pragma unroll
            for (int f = 0; f < 4; ++f) {
                short8 b = *reinterpret_cast<const short8*>(bb + f * 16 * 512 + k0);
                acc[f] = MFMA16(a, b, acc[f]);
            }
        }
        float part[4] = {0.f, 0.f, 0.f, 0.f};
#pragma unroll
        for (int f = 0; f < 4; ++f) {
            int n = w * 64 + f * 16 + l15;        // 0..255
            float b1 = bfc1[n], w5 = wfc5[n];
#pragma unroll
            for (int i = 0; i < 4; ++i) {
                float v = acc[f][i] + b1;
                v = v >= 0.f ? v : 0.1f * v;      // leaky relu
                part[i] = fmaf(v, w5, part[i]);
            }
        }
        float* red = smem;                        // [16][72]
#pragma unroll
        for (int i = 0; i < 4; ++i) red[(g * 4 + i) * 72 + w * 16 + l15] = part[i];
        __syncthreads();
        if (tid < 16) {
            float s = 0.f;
            for (int j = 0; j < 64; ++j) s += red[tid * 72 + j];
            out[m0 + tid] = 1.f / (1.f + expf(-(s + bfc5[0])));
        }
    }
}

// ---------------------------------------------------------------------------
extern "C" void kernel_launch(void* const* d_in, const int* in_sizes, int n_in,
                              void* d_out, int out_size, void* d_ws, size_t ws_size,
                              hipStream_t stream)
{
    const float* x    = (const float*)d_in[0];
    const float* wip  = (const float*)d_in[1];
    const float* cw   = (const float*)d_in[2];
    const float* cb   = (const float*)d_in[3];
    const float* wxp  = (const float*)d_in[4];
    const float* wdt  = (const float*)d_in[5];
    const float* bdt  = (const float*)d_in[6];
    // d_in[7] = A_log: unused — h0 == 0 at L==1 so dA never contributes.
    const float* Dv   = (const float*)d_in[8];
    const float* wout = (const float*)d_in[9];
    const float* wfc1 = (const float*)d_in[10];
    const float* bfc1 = (const float*)d_in[11];
    const float* wfc5 = (const float*)d_in[12];
    const float* bfc5 = (const float*)d_in[13];
    float* out = (float*)d_out;

    unsigned short* wsb = (unsigned short*)d_ws;
    unsigned* bar = (unsigned*)(wsb + O_END);     // barrier counter (poisoned -> zero it)

    hipMemsetAsync(bar, 0, 64, stream);
    k_net<<<NBLK, 256, 0, stream>>>(x, wip, wxp, wdt, wout, wfc1,
                                    cw, cb, bdt, Dv, bfc1, wfc5, bfc5,
                                    wsb, bar, out);
}

// Round 7
// 232.130 us; speedup vs baseline: 1.0325x; 1.0325x over previous
//
#include <hip/hip_runtime.h>
#include <hip/hip_bf16.h>
#include <cstddef>

typedef __attribute__((ext_vector_type(8))) short short8;   // 8 x bf16
typedef __attribute__((ext_vector_type(4))) float f32x4;    // MFMA accumulator

#define MFMA16(a, b, c) __builtin_amdgcn_mfma_f32_16x16x32_bf16((a), (b), (c), 0, 0, 0)
#define NBLK 256

static __device__ __forceinline__ unsigned short f2bf(float f) {   // RNE
    unsigned int u = __float_as_uint(f);
    u = (u + 0x7FFFu + ((u >> 16) & 1u)) >> 16;
    return (unsigned short)u;
}
static __device__ __forceinline__ float bf2f(unsigned short h) {
    return __uint_as_float(((unsigned int)h) << 16);
}
static __device__ __forceinline__ float silu_f(float v) { return v / (1.f + expf(-v)); }

// 8 x f32 -> 8 x bf16 fragment via v_cvt_pk_bf16_f32 (no builtin on gfx950; T12/m240)
static __device__ __forceinline__ short8 cvt_frag(const float* __restrict__ p) {
    float4 a = *reinterpret_cast<const float4*>(p);
    float4 b = *reinterpret_cast<const float4*>(p + 4);
    union { short8 s; unsigned int u[4]; } r;
    asm("v_cvt_pk_bf16_f32 %0, %1, %2" : "=v"(r.u[0]) : "v"(a.x), "v"(a.y));
    asm("v_cvt_pk_bf16_f32 %0, %1, %2" : "=v"(r.u[1]) : "v"(a.z), "v"(a.w));
    asm("v_cvt_pk_bf16_f32 %0, %1, %2" : "=v"(r.u[2]) : "v"(b.x), "v"(b.y));
    asm("v_cvt_pk_bf16_f32 %0, %1, %2" : "=v"(r.u[3]) : "v"(b.z), "v"(b.w));
    return r.s;
}

// ws layout (bf16 element offsets; activations only — weights read f32 from d_in)
enum : size_t {
    O_XIN  = 0,                        // 512 x 1024
    O_SZ   = O_XIN  + 512 * 1024,      // 512 x 1024
    O_XDBL = O_SZ   + 512 * 1024,      // 512 x 288
    O_Y    = O_XDBL + 512 * 288,       // 512 x 1024
    O_MOUT = O_Y    + 512 * 1024,      // 512 x 512
    O_END  = O_MOUT + 512 * 512,       // barrier cnt/flag (16B-aligned)
};

// Fence-based flag barrier: relaxed polls (no per-iteration invalidate),
// one release fence before arrival, one acquire fence after exit.
static __device__ __forceinline__ void grid_barrier(unsigned* bar, unsigned phase)
{
    unsigned* cnt  = bar;        // arrival counter (reset by last arriver)
    unsigned* flag = bar + 16;   // monotonic phase flag, separate cacheline
    __syncthreads();
    if (threadIdx.x == 0) {
        __builtin_amdgcn_fence(__ATOMIC_RELEASE, "agent");
        unsigned old = __hip_atomic_fetch_add(cnt, 1u, __ATOMIC_RELAXED,
                                              __HIP_MEMORY_SCOPE_AGENT);
        if (old == NBLK - 1) {
            __hip_atomic_store(cnt, 0u, __ATOMIC_RELAXED, __HIP_MEMORY_SCOPE_AGENT);
            __hip_atomic_store(flag, phase, __ATOMIC_RELEASE, __HIP_MEMORY_SCOPE_AGENT);
        } else {
            while (__hip_atomic_load(flag, __ATOMIC_RELAXED,
                                     __HIP_MEMORY_SCOPE_AGENT) < phase)
                __builtin_amdgcn_s_sleep(4);
        }
        __builtin_amdgcn_fence(__ATOMIC_ACQUIRE, "agent");
    }
    __syncthreads();
}

// ---------------------------------------------------------------------------
// Persistent kernel: 5 phases, 4 grid barriers, 256 blocks x 512 threads.
// ---------------------------------------------------------------------------
__global__ __launch_bounds__(512, 2) void k_net(
    const float* __restrict__ x,    const float* __restrict__ wip,
    const float* __restrict__ wxp,  const float* __restrict__ wdt,
    const float* __restrict__ wout, const float* __restrict__ wfc1,
    const float* __restrict__ cw,   const float* __restrict__ cb,
    const float* __restrict__ dtb,  const float* __restrict__ Dv,
    const float* __restrict__ bfc1, const float* __restrict__ wfc5,
    const float* __restrict__ bfc5,
    unsigned short* __restrict__ wsb, unsigned* __restrict__ bar,
    float* __restrict__ out)
{
    __shared__ float smem[16 * 18];           // phase C: bcp[16][17]+bc[16]; phase E: red[16][8]
    const int tid  = threadIdx.x;
    const int bid  = blockIdx.x;
    const int w    = tid >> 6;                // wave 0..7
    const int lane = tid & 63;
    const int l15  = lane & 15;
    const int g    = lane >> 4;               // k-group 0..3

    // ========== phase A: xz = x @ wip^T (M=512,N=2048,K=512) + conv/silu ====
    // 16 n-tiles(128) x 16 m-tiles(32); same n-tile -> same XCD (weight L2 reuse).
    {
        const int xcd = bid & 7, idx = bid >> 3;
        const int n_t = (idx & 1) * 8 + xcd;       // 0..15
        const int m_t = idx >> 1;                  // 0..15
        const int wr = w >> 2, wc = w & 3;
        const int m0 = m_t * 32 + wr * 16;
        const int n0 = n_t * 128 + wc * 32;
        const float* arow = x + (size_t)(m0 + l15) * 512 + g * 8;
        const float* brow = wip + (size_t)(n0 + l15) * 512 + g * 8;

        f32x4 acc[2] = {};
#pragma unroll 4
        for (int k0 = 0; k0 < 512; k0 += 32) {
            short8 a = cvt_frag(arow + k0);
#pragma unroll
            for (int f = 0; f < 2; ++f) {
                short8 b = cvt_frag(brow + (size_t)f * 16 * 512 + k0);
                acc[f] = MFMA16(a, b, acc[f]);
            }
        }
        const bool xhalf = (n_t < 8);
        unsigned short* dst = wsb + (xhalf ? O_XIN : O_SZ);
#pragma unroll
        for (int f = 0; f < 2; ++f) {
            int n = n0 + f * 16 + l15;             // 0..2047
            int c = xhalf ? n : n - 1024;
            float cwv = 0.f, cbv = 0.f;
            if (xhalf) { cwv = cw[2 * n + 1]; cbv = cb[n]; }
#pragma unroll
            for (int i = 0; i < 4; ++i) {
                int r = m0 + g * 4 + i;
                float v = acc[f][i];
                v = xhalf ? silu_f(cbv + cwv * v) : silu_f(v);
                dst[(size_t)r * 1024 + c] = f2bf(v);
            }
        }
    }
    grid_barrier(bar, 1);

    // ========== phase B: xdbl = xin @ wxp^T (M=512,N=288,K=1024) ============
    // 576 wave units (18 n x 32 m), one 16x16 tile each.
    {
        const int u = bid * 8 + w;
        if (u < 576) {
            const int n_t = u % 18, m_t = u / 18;
            const unsigned short* ab = wsb + O_XIN + (size_t)(m_t * 16 + l15) * 1024 + g * 8;
            const float* brow = wxp + (size_t)(n_t * 16 + l15) * 1024 + g * 8;
            f32x4 acc = {};
#pragma unroll 4
            for (int k0 = 0; k0 < 1024; k0 += 32) {
                short8 a = *reinterpret_cast<const short8*>(ab + k0);
                short8 b = cvt_frag(brow + k0);
                acc = MFMA16(a, b, acc);
            }
            unsigned short* xd = wsb + O_XDBL;
#pragma unroll
            for (int i = 0; i < 4; ++i)
                xd[(size_t)(m_t * 16 + g * 4 + i) * 288 + n_t * 16 + l15] = f2bf(acc[i]);
        }
    }
    grid_barrier(bar, 2);

    // ========== phase C: dt/softplus + bc + y (M=512,N=1024,K=32) ===========
    // 64 blocks: 32 m-tiles(16) x 2 n-halves(512); wave = 16 rows x 64 cols.
    if (bid < 64) {
        const int m0 = (bid >> 1) * 16;
        const int nh = (bid & 1) * 512;
        const unsigned short* xd = wsb + O_XDBL;
        float* bcp  = smem;              // [16][17]
        float* bc_s = smem + 16 * 17;    // [16]
        if (tid < 256) {                 // bc[r] = sum_{s<128} Bm[r,s]*Cm[r,s]
            int r = tid >> 4, p = tid & 15;
            const unsigned short* row = xd + (size_t)(m0 + r) * 288;
            float s = 0.f;
#pragma unroll
            for (int q = 0; q < 8; ++q)
                s += bf2f(row[32 + p * 8 + q]) * bf2f(row[160 + p * 8 + q]);
            bcp[r * 17 + p] = s;
        }
        short8 a = *reinterpret_cast<const short8*>(xd + (size_t)(m0 + l15) * 288 + g * 8);
        __syncthreads();
        if (tid < 16) {
            float s = 0.f;
#pragma unroll
            for (int p = 0; p < 16; ++p) s += bcp[tid * 17 + p];
            bc_s[tid] = s;
        }
        __syncthreads();

        const unsigned short* xinb = wsb + O_XIN;
        const unsigned short* szb  = wsb + O_SZ;
        unsigned short* yb = wsb + O_Y;
        const f32x4 z4 = {0.f, 0.f, 0.f, 0.f};
#pragma unroll
        for (int f = 0; f < 4; ++f) {
            int n = nh + w * 64 + f * 16 + l15;    // 0..1023
            short8 b = cvt_frag(wdt + (size_t)n * 32 + g * 8);
            f32x4 acc = MFMA16(a, b, z4);
            float dtbv = dtb[n], Dvv = Dv[n];
#pragma unroll
            for (int i = 0; i < 4; ++i) {
                int r = m0 + g * 4 + i;
                float dtv = acc[i] + dtbv;
                dtv = (dtv > 20.f) ? dtv : log1pf(expf(dtv));   // softplus
                float yv = bf2f(xinb[(size_t)r * 1024 + n]) *
                           (dtv * bc_s[g * 4 + i] + Dvv) *
                           bf2f(szb[(size_t)r * 1024 + n]);
                yb[(size_t)r * 1024 + n] = f2bf(yv);
            }
        }
    }
    grid_barrier(bar, 3);

    // ========== phase D: mout = y @ wout^T (M=512,N=512,K=1024) =============
    // 128 blocks: 32 m-tiles(16) x 4 n-quarters(128); wave = 16x16 tile.
    if (bid < 128) {
        const int m0 = (bid >> 2) * 16;
        const int n0 = (bid & 3) * 128 + w * 16;
        const unsigned short* ab = wsb + O_Y + (size_t)(m0 + l15) * 1024 + g * 8;
        const float* brow = wout + (size_t)(n0 + l15) * 1024 + g * 8;
        f32x4 acc = {};
#pragma unroll 4
        for (int k0 = 0; k0 < 1024; k0 += 32) {
            short8 a = *reinterpret_cast<const short8*>(ab + k0);
            short8 b = cvt_frag(brow + k0);
            acc = MFMA16(a, b, acc);
        }
        unsigned short* mo = wsb + O_MOUT;
#pragma unroll
        for (int i = 0; i < 4; ++i)
            mo[(size_t)(m0 + g * 4 + i) * 512 + n0 + l15] = f2bf(acc[i]);
    }
    grid_barrier(bar, 4);

    // ========== phase E: fc1 + head (M=512,N=256,K=512), 32 blocks ==========
    if (bid < 32) {
        const int m0 = bid * 16;
        const unsigned short* ab = wsb + O_MOUT + (size_t)(m0 + l15) * 512 + g * 8;
        const float* brow = wfc1 + (size_t)(w * 32 + l15) * 512 + g * 8;
        f32x4 acc[2] = {};
#pragma unroll 4
        for (int k0 = 0; k0 < 512; k0 += 32) {
            short8 a = *reinterpret_cast<const short8*>(ab + k0);
#pragma unroll
            for (int f = 0; f < 2; ++f) {
                short8 b = cvt_frag(brow + (size_t)f * 16 * 512 + k0);
                acc[f] = MFMA16(a, b, acc[f]);
            }
        }
        float part[4] = {0.f, 0.f, 0.f, 0.f};
#pragma unroll
        for (int f = 0; f < 2; ++f) {
            int n = w * 32 + f * 16 + l15;         // 0..255
            float b1 = bfc1[n], w5 = wfc5[n];
#pragma unroll
            for (int i = 0; i < 4; ++i) {
                float v = acc[f][i] + b1;
                v = v >= 0.f ? v : 0.1f * v;       // leaky relu
                part[i] = fmaf(v, w5, part[i]);
            }
        }
        // reduce over the 16 col-lanes within each k-group (rows differ per g)
#pragma unroll
        for (int off = 1; off < 16; off <<= 1)
#pragma unroll
            for (int i = 0; i < 4; ++i) part[i] += __shfl_xor(part[i], off, 64);
        float* red = smem;                         // [16][8]
        if (l15 == 0)
#pragma unroll
            for (int i = 0; i < 4; ++i) red[(g * 4 + i) * 8 + w] = part[i];
        __syncthreads();
        if (tid < 16) {
            float s = 0.f;
#pragma unroll
            for (int j = 0; j < 8; ++j) s += red[tid * 8 + j];
            out[m0 + tid] = 1.f / (1.f + expf(-(s + bfc5[0])));
        }
    }
}

// ---------------------------------------------------------------------------
extern "C" void kernel_launch(void* const* d_in, const int* in_sizes, int n_in,
                              void* d_out, int out_size, void* d_ws, size_t ws_size,
                              hipStream_t stream)
{
    const float* x    = (const float*)d_in[0];
    const float* wip  = (const float*)d_in[1];
    const float* cw   = (const float*)d_in[2];
    const float* cb   = (const float*)d_in[3];
    const float* wxp  = (const float*)d_in[4];
    const float* wdt  = (const float*)d_in[5];
    const float* bdt  = (const float*)d_in[6];
    // d_in[7] = A_log: unused — h0 == 0 at L==1 so dA never contributes.
    const float* Dv   = (const float*)d_in[8];
    const float* wout = (const float*)d_in[9];
    const float* wfc1 = (const float*)d_in[10];
    const float* bfc1 = (const float*)d_in[11];
    const float* wfc5 = (const float*)d_in[12];
    const float* bfc5 = (const float*)d_in[13];
    float* out = (float*)d_out;

    unsigned short* wsb = (unsigned short*)d_ws;
    unsigned* bar = (unsigned*)(wsb + O_END);     // cnt + flag (poisoned -> zero)

    hipMemsetAsync(bar, 0, 128, stream);
    k_net<<<NBLK, 512, 0, stream>>>(x, wip, wxp, wdt, wout, wfc1,
                                    cw, cb, bdt, Dv, bfc1, wfc5, bfc5,
                                    wsb, bar, out);
}

// Round 8
// 147.707 us; speedup vs baseline: 1.6226x; 1.5716x over previous
//
#include <hip/hip_runtime.h>
#include <hip/hip_bf16.h>
#include <cstddef>

typedef __attribute__((ext_vector_type(8))) short short8;   // 8 x bf16
typedef __attribute__((ext_vector_type(4))) float f32x4;    // MFMA accumulator

#define MFMA16(a, b, c) __builtin_amdgcn_mfma_f32_16x16x32_bf16((a), (b), (c), 0, 0, 0)

static __device__ __forceinline__ unsigned short f2bf(float f) {   // RNE
    unsigned int u = __float_as_uint(f);
    u = (u + 0x7FFFu + ((u >> 16) & 1u)) >> 16;
    return (unsigned short)u;
}
static __device__ __forceinline__ float bf2f(unsigned short h) {
    return __uint_as_float(((unsigned int)h) << 16);
}
static __device__ __forceinline__ float silu_f(float v) { return v / (1.f + expf(-v)); }

// ws layout (bf16 element offsets, all multiples of 8 -> 16B aligned)
enum : size_t {
    O_X    = 0,                        // 512 x 512
    O_WIP  = O_X    + 512 * 512,       // 2048 x 512
    O_WXP  = O_WIP  + 2048 * 512,      // 288 x 1024
    O_WDT  = O_WXP  + 288 * 1024,      // 1024 x 32
    O_WOUT = O_WDT  + 1024 * 32,       // 512 x 1024
    O_WFC1 = O_WOUT + 512 * 1024,      // 256 x 512
    O_XIN  = O_WFC1 + 256 * 512,       // 512 x 1024
    O_SZ   = O_XIN  + 512 * 1024,      // 512 x 1024
    O_XDBL = O_SZ   + 512 * 1024,      // 512 x 288
    O_Y    = O_XDBL + 512 * 288,       // 512 x 1024
    O_MOUT = O_Y    + 512 * 1024,      // 512 x 512
};

// ---------------------------------------------------------------------------
// k_convert: cast x + 5 weight matrices f32 -> bf16 into ws (single-use data
// staged once; halves every downstream per-CU weight stream).
// ---------------------------------------------------------------------------
static __device__ __forceinline__ void cvt_seg(const float* __restrict__ s,
                                               unsigned short* __restrict__ d,
                                               int n, int gt, int np)
{
    for (int i = gt * 4; i < n; i += np * 4) {
        float4 v = *reinterpret_cast<const float4*>(s + i);
        ushort4 o;
        o.x = f2bf(v.x); o.y = f2bf(v.y); o.z = f2bf(v.z); o.w = f2bf(v.w);
        *reinterpret_cast<ushort4*>(d + i) = o;
    }
}

__global__ __launch_bounds__(256) void k_convert(
    const float* __restrict__ x,    const float* __restrict__ wip,
    const float* __restrict__ wxp,  const float* __restrict__ wdt,
    const float* __restrict__ wout, const float* __restrict__ wfc1,
    unsigned short* __restrict__ dst)
{
    const int gt = blockIdx.x * blockDim.x + threadIdx.x;
    const int np = gridDim.x * blockDim.x;
    cvt_seg(x,    dst + O_X,    512 * 512,  gt, np);
    cvt_seg(wip,  dst + O_WIP,  2048 * 512, gt, np);
    cvt_seg(wxp,  dst + O_WXP,  288 * 1024, gt, np);
    cvt_seg(wdt,  dst + O_WDT,  1024 * 32,  gt, np);
    cvt_seg(wout, dst + O_WOUT, 512 * 1024, gt, np);
    cvt_seg(wfc1, dst + O_WFC1, 256 * 512,  gt, np);
}

// ---------------------------------------------------------------------------
// Stage 1: xz = x @ in_proj_w^T (M=512, N=2048, K=512) + conv/silu epilogue.
// Grid (32 n-tiles, 8 m-tiles) = 256 blocks; wave = 16 rows x 64 cols.
// nx=32 % 8 == 0 -> all m-tiles of an n-tile land on one XCD (weight reuse).
// ---------------------------------------------------------------------------
__global__ __launch_bounds__(256, 2) void k_s1(
    unsigned short* __restrict__ wsb,
    const float* __restrict__ cw, const float* __restrict__ cb)
{
    const int tid = threadIdx.x;
    const int w = tid >> 6, lane = tid & 63, l15 = lane & 15, g = lane >> 4;
    const int n0 = blockIdx.x * 64;
    const int m0 = blockIdx.y * 64 + w * 16;

    const unsigned short* ab = wsb + O_X   + (size_t)(m0 + l15) * 512 + g * 8;
    const unsigned short* bb = wsb + O_WIP + (size_t)(n0 + l15) * 512 + g * 8;

    f32x4 acc[4] = {};
#pragma unroll 4
    for (int k0 = 0; k0 < 512; k0 += 32) {
        short8 a = *reinterpret_cast<const short8*>(ab + k0);
#pragma unroll
        for (int f = 0; f < 4; ++f) {
            short8 b = *reinterpret_cast<const short8*>(bb + f * 16 * 512 + k0);
            acc[f] = MFMA16(a, b, acc[f]);
        }
    }

    const bool xhalf = (n0 < 1024);
    unsigned short* dst = wsb + (xhalf ? O_XIN : O_SZ);
#pragma unroll
    for (int f = 0; f < 4; ++f) {
        int n = n0 + f * 16 + l15;                 // global col 0..2047
        int c = xhalf ? n : n - 1024;              // col in 0..1023
        float cwv = 0.f, cbv = 0.f;
        if (xhalf) { cwv = cw[2 * n + 1]; cbv = cb[n]; }
#pragma unroll
        for (int i = 0; i < 4; ++i) {
            int r = m0 + g * 4 + i;
            float v = acc[f][i];
            v = xhalf ? silu_f(cbv + cwv * v) : silu_f(v);
            dst[(size_t)r * 1024 + c] = f2bf(v);
        }
    }
}

// ---------------------------------------------------------------------------
// Stage 2: xdbl = xin @ x_proj_w^T (M=512, N=288, K=1024).
// Grid (18 n-tiles, 8 m-tiles) = 144 blocks; wave = 16x16 tile.
// ---------------------------------------------------------------------------
__global__ __launch_bounds__(256, 2) void k_s2(unsigned short* __restrict__ wsb)
{
    const int tid = threadIdx.x;
    const int w = tid >> 6, lane = tid & 63, l15 = lane & 15, g = lane >> 4;
    const int n0 = blockIdx.x * 16;
    const int m0 = blockIdx.y * 64 + w * 16;

    const unsigned short* ab = wsb + O_XIN + (size_t)(m0 + l15) * 1024 + g * 8;
    const unsigned short* bb = wsb + O_WXP + (size_t)(n0 + l15) * 1024 + g * 8;

    f32x4 acc = {};
#pragma unroll 4
    for (int k0 = 0; k0 < 1024; k0 += 32) {
        short8 a = *reinterpret_cast<const short8*>(ab + k0);
        short8 b = *reinterpret_cast<const short8*>(bb + k0);
        acc = MFMA16(a, b, acc);
    }
    unsigned short* xd = wsb + O_XDBL;
#pragma unroll
    for (int i = 0; i < 4; ++i)
        xd[(size_t)(m0 + g * 4 + i) * 288 + n0 + l15] = f2bf(acc[i]);
}

// ---------------------------------------------------------------------------
// Stage 3: dt = softplus(xdbl[:, :32] @ dt_proj_w^T + b); bc[r] = Bm.Cm (128
// terms); y = xin * (dt*bc + D) * sz.  (M=512, N=1024, K=32)
// Grid (4 n-tiles of 256, 32 m-tiles of 16) = 128 blocks.
// ---------------------------------------------------------------------------
__global__ __launch_bounds__(256, 2) void k_s3(
    unsigned short* __restrict__ wsb,
    const float* __restrict__ dtb, const float* __restrict__ Dv)
{
    __shared__ float bcp[16][17];
    __shared__ float bc_s[16];
    const int tid = threadIdx.x;
    const int w = tid >> 6, lane = tid & 63, l15 = lane & 15, g = lane >> 4;
    const int n0 = blockIdx.x * 256;
    const int m0 = blockIdx.y * 16;

    const unsigned short* xd = wsb + O_XDBL;
    {   // bc[r] = sum_{s<128} Bm[r,s]*Cm[r,s]  (cols 32..159 x 160..287)
        int r = tid >> 4, p = tid & 15;
        const unsigned short* row = xd + (size_t)(m0 + r) * 288;
        float s = 0.f;
#pragma unroll
        for (int q = 0; q < 8; ++q)
            s += bf2f(row[32 + p * 8 + q]) * bf2f(row[160 + p * 8 + q]);
        bcp[r][p] = s;
    }
    short8 a = *reinterpret_cast<const short8*>(xd + (size_t)(m0 + l15) * 288 + g * 8);
    __syncthreads();
    if (tid < 16) {
        float s = 0.f;
#pragma unroll
        for (int p = 0; p < 16; ++p) s += bcp[tid][p];
        bc_s[tid] = s;
    }
    __syncthreads();

    const unsigned short* wdtb = wsb + O_WDT;
    const unsigned short* xinb = wsb + O_XIN;
    const unsigned short* szb  = wsb + O_SZ;
    unsigned short* yb = wsb + O_Y;
    const f32x4 z4 = {0.f, 0.f, 0.f, 0.f};
#pragma unroll
    for (int f = 0; f < 4; ++f) {
        int n = n0 + w * 64 + f * 16 + l15;        // 0..1023
        short8 b = *reinterpret_cast<const short8*>(wdtb + (size_t)n * 32 + g * 8);
        f32x4 acc = MFMA16(a, b, z4);
        float dtbv = dtb[n], Dvv = Dv[n];
#pragma unroll
        for (int i = 0; i < 4; ++i) {
            int r = m0 + g * 4 + i;
            float dtv = acc[i] + dtbv;
            dtv = (dtv > 20.f) ? dtv : log1pf(expf(dtv));   // softplus
            float yv = bf2f(xinb[(size_t)r * 1024 + n]) *
                       (dtv * bc_s[g * 4 + i] + Dvv) *
                       bf2f(szb[(size_t)r * 1024 + n]);
            yb[(size_t)r * 1024 + n] = f2bf(yv);
        }
    }
}

// ---------------------------------------------------------------------------
// Stage 4: mout = y @ out_proj_w^T (M=512, N=512, K=1024).
// Grid (8 n-tiles of 64, 32 m-tiles of 16) = 256 blocks; wave = 16x16 tile;
// per-block weight slice = 128 KB bf16 (~1 us of per-CU L2 stream).
// ---------------------------------------------------------------------------
__global__ __launch_bounds__(256, 2) void k_s4(unsigned short* __restrict__ wsb)
{
    const int tid = threadIdx.x;
    const int w = tid >> 6, lane = tid & 63, l15 = lane & 15, g = lane >> 4;
    const int n0 = blockIdx.x * 64 + w * 16;
    const int m0 = blockIdx.y * 16;

    const unsigned short* ab = wsb + O_Y    + (size_t)(m0 + l15) * 1024 + g * 8;
    const unsigned short* bb = wsb + O_WOUT + (size_t)(n0 + l15) * 1024 + g * 8;

    f32x4 acc = {};
#pragma unroll 4
    for (int k0 = 0; k0 < 1024; k0 += 32) {
        short8 a = *reinterpret_cast<const short8*>(ab + k0);
        short8 b = *reinterpret_cast<const short8*>(bb + k0);
        acc = MFMA16(a, b, acc);
    }
    unsigned short* mo = wsb + O_MOUT;
#pragma unroll
    for (int i = 0; i < 4; ++i)
        mo[(size_t)(m0 + g * 4 + i) * 512 + n0 + l15] = f2bf(acc[i]);
}

// ---------------------------------------------------------------------------
// Stage 5: h1 = mout @ fc1_w^T (M=512, N=256, K=512) fused with the head:
//   out[b] = sigmoid(fc5_b + sum_j fc5_w[j] * leaky(h1[b,j] + fc1_b[j])).
// Grid 32 blocks (16 rows each); wave w = cols w*64..; LDS reduce.
// ---------------------------------------------------------------------------
__global__ __launch_bounds__(256, 2) void k_s5(
    unsigned short* __restrict__ wsb,
    const float* __restrict__ bfc1, const float* __restrict__ wfc5,
    const float* __restrict__ bfc5, float* __restrict__ out)
{
    __shared__ float red[16][72];
    const int tid = threadIdx.x;
    const int w = tid >> 6, lane = tid & 63, l15 = lane & 15, g = lane >> 4;
    const int m0 = blockIdx.x * 16;

    const unsigned short* ab = wsb + O_MOUT + (size_t)(m0 + l15) * 512 + g * 8;
    const unsigned short* bb = wsb + O_WFC1 + (size_t)(w * 64 + l15) * 512 + g * 8;

    f32x4 acc[4] = {};
#pragma unroll 4
    for (int k0 = 0; k0 < 512; k0 += 32) {
        short8 a = *reinterpret_cast<const short8*>(ab + k0);
#pragma unroll
        for (int f = 0; f < 4; ++f) {
            short8 b = *reinterpret_cast<const short8*>(bb + f * 16 * 512 + k0);
            acc[f] = MFMA16(a, b, acc[f]);
        }
    }
    float part[4] = {0.f, 0.f, 0.f, 0.f};
#pragma unroll
    for (int f = 0; f < 4; ++f) {
        int n = w * 64 + f * 16 + l15;             // 0..255
        float b1 = bfc1[n], w5 = wfc5[n];
#pragma unroll
        for (int i = 0; i < 4; ++i) {
            float v = acc[f][i] + b1;
            v = v >= 0.f ? v : 0.1f * v;           // leaky relu
            part[i] = fmaf(v, w5, part[i]);
        }
    }
#pragma unroll
    for (int i = 0; i < 4; ++i) red[g * 4 + i][w * 16 + l15] = part[i];
    __syncthreads();
    if (tid < 16) {
        float s = 0.f;
        for (int j = 0; j < 64; ++j) s += red[tid][j];
        out[m0 + tid] = 1.f / (1.f + expf(-(s + bfc5[0])));
    }
}

// ---------------------------------------------------------------------------
extern "C" void kernel_launch(void* const* d_in, const int* in_sizes, int n_in,
                              void* d_out, int out_size, void* d_ws, size_t ws_size,
                              hipStream_t stream)
{
    const float* x    = (const float*)d_in[0];
    const float* wip  = (const float*)d_in[1];
    const float* cw   = (const float*)d_in[2];
    const float* cb   = (const float*)d_in[3];
    const float* wxp  = (const float*)d_in[4];
    const float* wdt  = (const float*)d_in[5];
    const float* bdt  = (const float*)d_in[6];
    // d_in[7] = A_log: unused — h0 == 0 at L==1 so dA never contributes.
    const float* Dv   = (const float*)d_in[8];
    const float* wout = (const float*)d_in[9];
    const float* wfc1 = (const float*)d_in[10];
    const float* bfc1 = (const float*)d_in[11];
    const float* wfc5 = (const float*)d_in[12];
    const float* bfc5 = (const float*)d_in[13];
    float* out = (float*)d_out;

    unsigned short* wsb = (unsigned short*)d_ws;   // bf16 staging + activations

    k_convert<<<dim3(512),   256, 0, stream>>>(x, wip, wxp, wdt, wout, wfc1, wsb);
    k_s1     <<<dim3(32, 8), 256, 0, stream>>>(wsb, cw, cb);
    k_s2     <<<dim3(18, 8), 256, 0, stream>>>(wsb);
    k_s3     <<<dim3(4, 32), 256, 0, stream>>>(wsb, bdt, Dv);
    k_s4     <<<dim3(8, 32), 256, 0, stream>>>(wsb);
    k_s5     <<<dim3(32),    256, 0, stream>>>(wsb, bfc1, wfc5, bfc5, out);
}